// Round 6
// baseline (718.837 us; speedup 1.0000x reference)
//
#include <hip/hip_runtime.h>
#include <math.h>

#define TMASK 524287   // 2^19 - 1
#define PM0 455773     // 73856093 % 2^19
#define PM1 475295     // 19349663 % 2^19
#define PM2 130999     // 83492791 % 2^19

typedef __attribute__((ext_vector_type(8))) short bf16x8;
typedef __attribute__((ext_vector_type(4))) float f32x4;

// Transposed-bf16 weight buffer layout in d_ws (element offsets, shorts):
#define OFF_W0   0       // [128][64]   (K=52  pad 64)
#define OFF_W1   8192    // [128][128]
#define OFF_W2   24576   // [128][192]  (K=180 pad 192)
#define OFF_W3   49152   // [128][128]
#define OFF_E    65536   // [64][128]   E,M contiguous (8 tiles)
#define OFF_P    81920   // [32][128]   P,MAT contiguous (6 tiles)
#define OFF_S    94208   // [64][128]   (4 tiles; over-read pad follows)
#define WT_TOTAL 102400
#define WT_ALLOC 110592  // + zero pad so NT=8 over-reads stay finite & in-bounds

// ws byte layout: wt(221184) | tab8 int8[16][524288][2] (16 MiB) | feat_pm uint[N][16]
#define WS_TAB8_OFF 221184
#define TAB8_BYTES  (16u*524288u*2u)
#define WS_FEAT_OFF (WS_TAB8_OFF + TAB8_BYTES)

#define TAB_SCALE   131072.0f
#define TAB_INV     (1.0f/131072.0f)

// ---- em_nerf4 LDS layout (per-wave arena x2 + shared small weights)
#define A_FB   0        // bf16[32][72]   (R2 f32[32][20] aliases, FB dead post-L2)
#define A_H    4608     // bf16[32][136]
#define A_HC   13312    // bf16[32][138]  (stride padded odd-dword)
#define A_LN   22144    // f32[128]
#define ARENA_B 22656
#define SWB_OFF 45312   // bf16[1024]
#define SWF_OFF 47360   // f32[1080]
#define LDS4_TOTAL 51680

struct Params {
  const float* x; const float* freq; const float* tables;
  const float* b0; const float* b1; const float* b2; const float* b3;
  const float* e_b1; const float* e_w2; const float* e_b2; const float* e_g; const float* e_be;
  const float* m_b1; const float* m_w2; const float* m_b2; const float* m_g; const float* m_be;
  const float* p_b1; const float* p_w2; const float* p_b2;
  const float* mat_b1; const float* mat_w2; const float* mat_b2;
  const float* s_b1; const float* s_w2; const float* s_b2;
  const short* wt;
  const unsigned* feat;
  float* out;
  int N;
  int res[16];
  // staging tables for em_nerf4
  const float* ssrc[18]; int sdst[18]; int scnt[18];
  const float* wsrc[5];  int wdst[5];  int wcnt[5];
};

struct HashParams {
  const float* x; const unsigned short* tab8; unsigned* feat; int N; int res[16];
};
struct TabPrepParams { const float* tables; unsigned* tab8; };
struct PrepParams {
  const float* src[9];
  int end[9]; int Nsrc[9]; int Ksrc[9]; int Kpad[9];
  short* wt;
};

__device__ __forceinline__ short f2bf(float f){
  union { float f; unsigned u; } v; v.f = f;
  unsigned r = v.u + 0x7fffu + ((v.u >> 16) & 1u);   // RNE
  return (short)(r >> 16);
}
__device__ __forceinline__ float bf2f(short s){
  union { unsigned u; float f; } v; v.u = ((unsigned)(unsigned short)s) << 16; return v.f;
}
__device__ __forceinline__ float sigmoid_(float v){ return 1.f/(1.f + expf(-v)); }

// ---------------- weight transpose+bf16 prep (+ zero pad region)
__global__ __launch_bounds__(256)
void prep_weights(PrepParams P)
{
  int id = blockIdx.x*256 + threadIdx.x;
  if (id >= WT_ALLOC) return;
  if (id >= WT_TOTAL) { P.wt[id] = 0; return; }
  int r = 0, base = 0;
  #pragma unroll
  for (int i = 0; i < 9; ++i) { if (id >= P.end[i]) { r = i+1; base = P.end[i]; } }
  const int rel = id - base;
  const int kp = P.Kpad[r];
  const int n = rel / kp;
  const int k = rel - n*kp;
  float v = 0.f;
  if (k < P.Ksrc[r]) v = P.src[r][k * P.Nsrc[r] + n];
  P.wt[id] = f2bf(v);
}

// ---------------- table quantize fp32 -> int8 (scale 2^17)
__global__ __launch_bounds__(256)
void tab_prep(TabPrepParams P)
{
  const unsigned id = blockIdx.x*256 + threadIdx.x;
  if (id >= 16u*524288u/2u) return;
  const float4 v = ((const float4*)P.tables)[id];
  int q0 = (int)fminf(fmaxf(rintf(v.x*TAB_SCALE), -127.f), 127.f);
  int q1 = (int)fminf(fmaxf(rintf(v.y*TAB_SCALE), -127.f), 127.f);
  int q2 = (int)fminf(fmaxf(rintf(v.z*TAB_SCALE), -127.f), 127.f);
  int q3 = (int)fminf(fmaxf(rintf(v.w*TAB_SCALE), -127.f), 127.f);
  unsigned pack = (q0 & 255) | ((q1 & 255) << 8) | ((q2 & 255) << 16) | ((q3 & 255) << 24);
  P.tab8[id] = pack;
}

// ---------------- XCD-partitioned hash gather: block b handles level (b & 15).
__global__ __launch_bounds__(256, 8)
void hash_encode8(HashParams P)
{
  const int b = blockIdx.x;
  const int l = b & 15;
  const int p = (b >> 4)*256 + threadIdx.x;
  if (p >= P.N) return;
  const float xs0 = fminf(fmaxf(P.x[p*3+0], 0.f), 1.f);
  const float xs1 = fminf(fmaxf(P.x[p*3+1], 0.f), 1.f);
  const float xs2 = fminf(fmaxf(P.x[p*3+2], 0.f), 1.f);
  const int res = P.res[l];
  const float rf = (float)(res-1);
  const float s0 = xs0*rf, s1 = xs1*rf, s2 = xs2*rf;
  int f0i = (int)s0; if (f0i > res-1) f0i = res-1;
  int f1i = (int)s1; if (f1i > res-1) f1i = res-1;
  int f2i = (int)s2; if (f2i > res-1) f2i = res-1;
  const float w0 = s0 - (float)f0i;
  const float w1 = s1 - (float)f1i;
  const float w2 = s2 - (float)f2i;
  int c0i = f0i+1; if (c0i > res-1) c0i = res-1;
  int c1i = f1i+1; if (c1i > res-1) c1i = res-1;
  int c2i = f2i+1; if (c2i > res-1) c2i = res-1;
  const int hx0 = (f0i*PM0) & TMASK, hx1 = (c0i*PM0) & TMASK;
  const int hy0 = (f1i*PM1) & TMASK, hy1 = (c1i*PM1) & TMASK;
  const int hz0 = (f2i*PM2) & TMASK, hz1 = (c2i*PM2) & TMASK;
  const unsigned short* tp = P.tab8 + ((size_t)l << 19);
  unsigned short tv[8];
  #pragma unroll
  for (int cn = 0; cn < 8; ++cn) {
    const int bx = (cn>>2)&1, by = (cn>>1)&1, bz = cn&1;
    const int hh = ((bx?hx1:hx0) + (by?hy1:hy0) + (bz?hz1:hz0)) & TMASK;
    tv[cn] = tp[hh];
  }
  float a0 = 0.f, a1 = 0.f;
  #pragma unroll
  for (int cn = 0; cn < 8; ++cn) {
    const int bx = (cn>>2)&1, by = (cn>>1)&1, bz = cn&1;
    const float cw = (bx?w0:1.f-w0)*(by?w1:1.f-w1)*(bz?w2:1.f-w2);
    a0 = fmaf(cw, (float)(int)(signed char)(tv[cn] & 0xff), a0);
    a1 = fmaf(cw, (float)(int)(signed char)(tv[cn] >> 8),   a1);
  }
  a0 *= TAB_INV; a1 *= TAB_INV;
  const unsigned pack = (unsigned)(unsigned short)f2bf(a0)
                      | ((unsigned)(unsigned short)f2bf(a1) << 16);
  P.feat[(size_t)p*16 + l] = pack;
}

// ================= compact looped MLP kernel (I-cache resident) =================
struct Seg  { int aoff, lda, kc, kwoff; };
struct Phase{ int wtoff, kpad, nseg, biasoff, outoff, ldo, ntw, relu; Seg seg[2]; };
__device__ static const Phase c_ph[7] = {
  { OFF_W0,  64, 1,   0, A_H,  136, 8, 1, {{A_FB, 72, 2,   0},{0,0,0,0}} },
  { OFF_W1, 128, 1, 128, A_H,  136, 8, 1, {{A_H, 136, 4,   0},{0,0,0,0}} },
  { OFF_W2, 192, 2, 256, A_H,  136, 8, 1, {{A_H, 136, 4,   0},{A_FB,72,2,128}} },
  { OFF_W3, 128, 1, 384, A_H,  136, 8, 1, {{A_H, 136, 4,   0},{0,0,0,0}} },
  { OFF_E,  128, 1, 512, A_HC, 138, 8, 0, {{A_H, 136, 4,   0},{0,0,0,0}} },
  { OFF_P,  128, 1, 640, A_HC, 106, 6, 1, {{A_H, 136, 4,   0},{0,0,0,0}} },
  { OFF_S,  128, 1, 736, A_HC,  74, 4, 1, {{A_H, 136, 4,   0},{0,0,0,0}} },
};
struct L2D { int stride, srcoff, K2, OC2, lnidx, tnh, woff, boff, slot, npass; };
__device__ static const L2D c_l2[5] = {
  { 138,  0, 64, 3,  0, 1,   0, 800,  0, 2 },   // E
  { 138, 64, 64, 3,  1, 1, 192, 803,  3, 2 },   // M
  { 106,  0, 32, 6, -1, 0, 384, 806,  6, 3 },   // P
  { 106, 32, 64, 3, -1, 0, 576, 812, 12, 2 },   // MAT
  {  74,  0, 64, 4, -1, 0, 768, 815, 15, 2 },   // S
};
__device__ static const int c_l2s[7] = {0,0,0,0,0,2,4};
__device__ static const int c_l2e[7] = {0,0,0,0,2,4,5};

__global__ __launch_bounds__(128)
void em_nerf4(Params P)
{
  __shared__ __align__(16) char smem[LDS4_TOTAL];
  const int tid = threadIdx.x;
  const int lane = tid & 63, wave = tid >> 6;
  char* arena = smem + wave*ARENA_B;
  short* FB  = (short*)(arena + A_FB);
  float* R2  = (float*)(arena + A_FB);     // alias: FB dead after trunk L2
  float* LN_ = (float*)(arena + A_LN);
  short* swb = (short*)(smem + SWB_OFF);
  float* swf = (float*)(smem + SWF_OFF);

  // ---- staging (looped, one code copy)
  #pragma clang loop unroll(disable)
  for (int r = 0; r < 18; ++r)
    for (int i = tid; i < P.scnt[r]; i += 128) swf[P.sdst[r] + i] = P.ssrc[r][i];
  #pragma clang loop unroll(disable)
  for (int r = 0; r < 5; ++r)
    for (int i = tid; i < P.wcnt[r]; i += 128) swb[P.wdst[r] + i] = f2bf(P.wsrc[r][i]);

  // ---- encode: hash feats from ws + freq bands
  const int p0pt = blockIdx.x*64 + wave*32;
  #pragma clang loop unroll(disable)
  for (int pass = 0; pass < 2; ++pass) {
    const int idx = lane + pass*64;
    const int pl = idx >> 2, lq = idx & 3;
    int gp = p0pt + pl; if (gp >= P.N) gp = P.N - 1;
    const uint4 v = *(const uint4*)(P.feat + (size_t)gp*16 + lq*4);
    *(uint4*)&FB[pl*72 + lq*8] = v;
  }
  if (lane < 32) {
    int gp = p0pt + lane; if (gp >= P.N) gp = P.N - 1;
    float fr = P.freq[gp];
    fr = fminf(fmaxf(fr, 1e6f), 1e12f);
    const float nf = (log10f(fr) - 6.f) * (1.f/6.f);
    float a = 3.14159274101257324f * nf;
    #pragma clang loop unroll(disable)
    for (int i = 0; i < 10; ++i) {
      FB[lane*72 + 32 + 2*i] = f2bf(sinf(a));
      FB[lane*72 + 33 + 2*i] = f2bf(cosf(a));
      a = a * 2.f;
    }
    #pragma clang loop unroll(disable)
    for (int k = 52; k < 64; ++k) FB[lane*72 + k] = 0;
  }
  __syncthreads();

  const int n0 = lane & 15, q = lane >> 4;

  // ---- phase loop: 7 MFMA layers + interleaved LN / head-l2
  #pragma clang loop unroll(disable)
  for (int p = 0; p < 7; ++p) {
    const Phase* ph = &c_ph[p];
    f32x4 acc0[8], acc1[8];
    #pragma unroll
    for (int i = 0; i < 8; ++i) { acc0[i] = (f32x4)(0.f); acc1[i] = (f32x4)(0.f); }
    const int kpad = ph->kpad, kp16 = kpad*16;
    #pragma clang loop unroll(disable)
    for (int s = 0; s < ph->nseg; ++s) {
      const Seg* sg = &ph->seg[s];
      const int lda = sg->lda, kcn = sg->kc;
      const short* Ap0 = (const short*)(arena + sg->aoff) + n0*lda + q*8;
      const short* Ap1 = Ap0 + 16*lda;
      const short* Bp  = P.wt + ph->wtoff + n0*kpad + sg->kwoff + q*8;
      #pragma clang loop unroll(disable)
      for (int kc = 0; kc < kcn; ++kc) {
        const bf16x8 a0 = *(const bf16x8*)(Ap0 + kc*32);
        const bf16x8 a1 = *(const bf16x8*)(Ap1 + kc*32);
        const short* bp = Bp + kc*32;
        #pragma unroll
        for (int nt = 0; nt < 8; ++nt) {
          const bf16x8 b = *(const bf16x8*)(bp + nt*kp16);
          acc0[nt] = __builtin_amdgcn_mfma_f32_16x16x32_bf16(a0, b, acc0[nt], 0, 0, 0);
          acc1[nt] = __builtin_amdgcn_mfma_f32_16x16x32_bf16(a1, b, acc1[nt], 0, 0, 0);
        }
      }
    }
    // epilogue (C layout: col=lane&15, row=(lane>>4)*4+reg)
    {
      short* outp = (short*)(arena + ph->outoff);
      const int ldo = ph->ldo, ntw = ph->ntw, relu = ph->relu;
      #pragma unroll
      for (int nt = 0; nt < 8; ++nt) {
        if (nt < ntw) {
          const float bv = swf[ph->biasoff + nt*16 + n0];
          #pragma unroll
          for (int r = 0; r < 4; ++r) {
            float v0 = acc0[nt][r] + bv;
            float v1 = acc1[nt][r] + bv;
            if (relu) { v0 = fmaxf(v0, 0.f); v1 = fmaxf(v1, 0.f); }
            outp[(q*4 + r)*ldo + nt*16 + n0]      = f2bf(v0);
            outp[(16 + q*4 + r)*ldo + nt*16 + n0] = f2bf(v1);
          }
        }
      }
    }
    // LN stats for E,M (after phase 4; raw pre-relu values)
    if (p == 4) {
      const int pp = lane & 31, head = lane >> 5;
      const short* row = (const short*)(arena + A_HC) + pp*138 + head*64;
      float s = 0.f;
      #pragma clang loop unroll_count(4)
      for (int k = 0; k < 64; ++k) s += bf2f(row[k]);
      const float mn = s * (1.f/64.f);
      float vv = 0.f;
      #pragma clang loop unroll_count(4)
      for (int k = 0; k < 64; ++k) { const float d = bf2f(row[k]) - mn; vv = fmaf(d,d,vv); }
      LN_[head*64 + pp]      = mn;
      LN_[head*64 + 32 + pp] = 1.f / sqrtf(vv*(1.f/64.f) + 1e-5f);
    }
    // head second layers owed after this phase
    #pragma clang loop unroll(disable)
    for (int d = c_l2s[p]; d < c_l2e[p]; ++d) {
      const L2D* L = &c_l2[d];
      const int oc = L->OC2, K2 = L->K2, np = L->npass;
      #pragma clang loop unroll(disable)
      for (int pass = 0; pass < np; ++pass) {
        const int t = lane + pass*64;
        if (t < oc*32) {
          const int pp = t & 31, j = t >> 5;
          const short* row = (const short*)(arena + A_HC) + pp*L->stride + L->srcoff;
          float acc = swf[L->boff + j];
          const short* wp = swb + L->woff + j;
          if (L->lnidx >= 0) {
            const float mn = LN_[L->lnidx*64 + pp], iv = LN_[L->lnidx*64 + 32 + pp];
            const int gb = 819 + L->lnidx*128;
            #pragma clang loop unroll_count(4)
            for (int k = 0; k < K2; ++k) {
              float xv = (bf2f(row[k]) - mn)*iv*swf[gb + k] + swf[gb + 64 + k];
              xv = fmaxf(xv, 0.f);
              acc = fmaf(xv, bf2f(wp[k*oc]), acc);
            }
          } else {
            #pragma clang loop unroll_count(4)
            for (int k = 0; k < K2; ++k)
              acc = fmaf(bf2f(row[k]), bf2f(wp[k*oc]), acc);   // inputs already relu'd
          }
          if (L->tnh) acc = tanhf(acc);
          R2[pp*20 + L->slot + j] = acc;
        }
      }
    }
  }

  // ---- final packing (TIME=0 -> cos(phases))
  if (lane < 32) {
    const int gp = p0pt + lane;
    if (gp < P.N) {
      const float* r = R2 + lane*20;
      float* o = P.out + (size_t)gp*13;
      o[0] = r[0]*cosf(r[6]);
      o[1] = r[1]*cosf(r[7]);
      o[2] = r[2]*cosf(r[8]);
      o[3] = r[3]*cosf(r[9]);
      o[4] = r[4]*cosf(r[10]);
      o[5] = r[5]*cosf(r[11]);
      o[6] = 1.f + sigmoid_(r[12])*10.f;
      o[7] = 1.f + sigmoid_(r[13])*2.f;
      o[8] = sigmoid_(r[14])*0.01f;
      o[9]  = r[15];
      o[10] = r[16];
      o[11] = r[17];
      o[12] = r[18];
    }
  }
}

// ================= fallback fused kernel (ws too small) =================
__global__ __launch_bounds__(256, 3)
void em_nerf_fallback(Params P)
{
  __shared__ __align__(16) char smem[44288];
  short* featB = (short*)smem;
  short* hA    = (short*)(smem + 9216);
  short* hB    = (short*)(smem + 9216 + 17664);
  float* headF = (float*)(smem + 9216);
  float* res2  = (float*)smem;
  __shared__ int s_res[16];

  const int tid = threadIdx.x;
  if (tid < 16) s_res[tid] = P.res[tid];
  __syncthreads();
  {
    const int p = tid & 63;
    const int g = tid >> 6;
    int gp = blockIdx.x*64 + p; if (gp >= P.N) gp = P.N - 1;
    const float xs0 = fminf(fmaxf(P.x[gp*3+0], 0.f), 1.f);
    const float xs1 = fminf(fmaxf(P.x[gp*3+1], 0.f), 1.f);
    const float xs2 = fminf(fmaxf(P.x[gp*3+2], 0.f), 1.f);
    #pragma unroll
    for (int j = 0; j < 4; ++j) {
      const int l = g*4 + j;
      const int res = s_res[l];
      const float rf = (float)(res-1);
      const float s0 = xs0*rf, s1 = xs1*rf, s2 = xs2*rf;
      int f0i = (int)s0; if (f0i > res-1) f0i = res-1;
      int f1i = (int)s1; if (f1i > res-1) f1i = res-1;
      int f2i = (int)s2; if (f2i > res-1) f2i = res-1;
      const float w0 = s0 - (float)f0i;
      const float w1 = s1 - (float)f1i;
      const float w2 = s2 - (float)f2i;
      int c0i = f0i+1; if (c0i > res-1) c0i = res-1;
      int c1i = f1i+1; if (c1i > res-1) c1i = res-1;
      int c2i = f2i+1; if (c2i > res-1) c2i = res-1;
      const int hx0 = (f0i*PM0) & TMASK, hx1 = (c0i*PM0) & TMASK;
      const int hy0 = (f1i*PM1) & TMASK, hy1 = (c1i*PM1) & TMASK;
      const int hz0 = (f2i*PM2) & TMASK, hz1 = (c2i*PM2) & TMASK;
      const float* tp = P.tables + ((size_t)l << 20);
      float a0 = 0.f, a1 = 0.f;
      #pragma unroll
      for (int cn = 0; cn < 8; ++cn) {
        const int bx = (cn>>2)&1, by = (cn>>1)&1, bz = cn&1;
        const int hh = ((bx?hx1:hx0) + (by?hy1:hy0) + (bz?hz1:hz0)) & TMASK;
        const float cw = (bx?w0:1.f-w0)*(by?w1:1.f-w1)*(bz?w2:1.f-w2);
        const float2 tv = *(const float2*)(tp + 2*hh);
        a0 = fmaf(cw, tv.x, a0);
        a1 = fmaf(cw, tv.y, a1);
      }
      featB[p*72 + 2*l]   = f2bf(a0);
      featB[p*72 + 2*l+1] = f2bf(a1);
    }
    if (g == 0) {
      float fr = P.freq[gp];
      fr = fminf(fmaxf(fr, 1e6f), 1e12f);
      const float nf = (log10f(fr) - 6.f) * (1.f/6.f);
      float a = 3.14159274101257324f * nf;
      #pragma unroll
      for (int i = 0; i < 10; ++i) {
        featB[p*72 + 32 + 2*i] = f2bf(sinf(a));
        featB[p*72 + 33 + 2*i] = f2bf(cosf(a));
        a = a * 2.f;
      }
    }
    if (g == 3) {
      #pragma unroll
      for (int k = 52; k < 64; ++k) featB[p*72 + k] = 0;
    }
  }
  __syncthreads();

  const int lane = tid & 63, wave = tid >> 6;
  const int n0 = lane & 15, q = lane >> 4;
  short* myA  = featB + wave*16*72;
  short* myH1 = hA + wave*16*136;
  short* myH2 = hB + wave*16*136;

  auto gemm1 = [&](const short* A, int lda, const short* wt, int kpad, int kwoff, int KC, f32x4* acc, int NT){
    const short* Ap = A + n0*lda + q*8;
    const short* Bp = wt + n0*kpad + kwoff + q*8;
    for (int kc = 0; kc < KC; ++kc) {
      bf16x8 a = *(const bf16x8*)(Ap + kc*32);
      for (int nt = 0; nt < NT; ++nt) {
        bf16x8 b = *(const bf16x8*)(Bp + nt*16*kpad + kc*32);
        acc[nt] = __builtin_amdgcn_mfma_f32_16x16x32_bf16(a, b, acc[nt], 0, 0, 0);
      }
    }
  };
  auto epi1 = [&](const f32x4* acc, const float* bias, short* out, int ldo, int NT, bool relu){
    for (int nt = 0; nt < NT; ++nt) {
      const float bv = bias[nt*16 + n0];
      for (int r = 0; r < 4; ++r) {
        float v = acc[nt][r] + bv;
        if (relu) v = fmaxf(v, 0.f);
        out[(q*4 + r)*ldo + nt*16 + n0] = f2bf(v);
      }
    }
  };

  { f32x4 acc[8] = {}; gemm1(myA, 72, P.wt + OFF_W0, 64, 0, 2, acc, 8);  epi1(acc, P.b0, myH1, 136, 8, true); }
  __syncthreads();
  { f32x4 acc[8] = {}; gemm1(myH1, 136, P.wt + OFF_W1, 128, 0, 4, acc, 8); epi1(acc, P.b1, myH2, 136, 8, true); }
  __syncthreads();
  { f32x4 acc[8] = {}; gemm1(myH2, 136, P.wt + OFF_W2, 192, 0, 4, acc, 8);
    gemm1(myA, 72, P.wt + OFF_W2, 192, 128, 2, acc, 8); epi1(acc, P.b2, myH1, 136, 8, true); }
  __syncthreads();
  { f32x4 acc[8] = {}; gemm1(myH1, 136, P.wt + OFF_W3, 128, 0, 4, acc, 8); epi1(acc, P.b3, myH2, 136, 8, true); }
  __syncthreads();

  float* hf = headF + wave*16*69;
  auto head1f = [&](const short* wt, const float* bias, int NT, bool relu){
    f32x4 acc[4] = {};
    gemm1(myH2, 136, wt, 128, 0, 4, acc, NT);
    for (int nt = 0; nt < NT; ++nt) {
      const float bv = bias[nt*16 + n0];
      for (int r = 0; r < 4; ++r) {
        float v = acc[nt][r] + bv;
        if (relu) v = fmaxf(v, 0.f);
        hf[(q*4 + r)*69 + nt*16 + n0] = v;
      }
    }
  };
  auto l2 = [&](int OC2, int K2, bool ln, bool th, const float* g, const float* be,
                const float* W2, const float* b2, int slot){
    __syncthreads();
    if (tid < 64) {
      const float* row = headF + tid*69;
      float mn = 0.f, iv = 1.f;
      if (ln) {
        float s = 0.f;
        for (int k = 0; k < K2; ++k) s += row[k];
        mn = s/(float)K2;
        float vv = 0.f;
        for (int k = 0; k < K2; ++k) { float d = row[k]-mn; vv = fmaf(d,d,vv); }
        iv = 1.f/sqrtf(vv/(float)K2 + 1e-5f);
      }
      for (int j = 0; j < OC2; ++j) {
        float acc = b2[j];
        for (int k = 0; k < K2; ++k) {
          float xv = row[k];
          if (ln) xv = (xv-mn)*iv*g[k] + be[k];
          xv = fmaxf(xv, 0.f);
          acc = fmaf(xv, W2[k*OC2+j], acc);
        }
        res2[tid*20 + slot + j] = th ? tanhf(acc) : acc;
      }
    }
    __syncthreads();
  };

  head1f(P.wt + OFF_E, P.e_b1, 4, false); l2(3, 64, true,  true,  P.e_g, P.e_be, P.e_w2, P.e_b2, 0);
  head1f(P.wt + OFF_E + 8192, P.m_b1, 4, false); l2(3, 64, true, true, P.m_g, P.m_be, P.m_w2, P.m_b2, 3);
  head1f(P.wt + OFF_P, P.p_b1, 2, true);  l2(6, 32, false, false, 0, 0, P.p_w2, P.p_b2, 6);
  head1f(P.wt + OFF_P + 4096, P.mat_b1, 4, true); l2(3, 64, false, false, 0, 0, P.mat_w2, P.mat_b2, 12);
  head1f(P.wt + OFF_S, P.s_b1, 4, true);  l2(4, 64, false, false, 0, 0, P.s_w2, P.s_b2, 15);

  if (tid < 64) {
    const int gp = blockIdx.x*64 + tid;
    if (gp < P.N) {
      const float* r = res2 + tid*20;
      float* o = P.out + (size_t)gp*13;
      o[0] = r[0]*cosf(r[6]);
      o[1] = r[1]*cosf(r[7]);
      o[2] = r[2]*cosf(r[8]);
      o[3] = r[3]*cosf(r[9]);
      o[4] = r[4]*cosf(r[10]);
      o[5] = r[5]*cosf(r[11]);
      o[6] = 1.f + sigmoid_(r[12])*10.f;
      o[7] = 1.f + sigmoid_(r[13])*2.f;
      o[8] = sigmoid_(r[14])*0.01f;
      o[9]  = r[15];
      o[10] = r[16];
      o[11] = r[17];
      o[12] = r[18];
    }
  }
}

extern "C" void kernel_launch(void* const* d_in, const int* in_sizes, int n_in,
                              void* d_out, int out_size, void* d_ws, size_t ws_size,
                              hipStream_t stream) {
  (void)n_in; (void)out_size;
  const float** in = (const float**)d_in;
  const int N = in_sizes[0] / 3;

  PrepParams PP;
  const float* srcs[9] = { in[3], in[5], in[7], in[9], in[11], in[15], in[19], in[23], in[27] };
  const int ends[9]  = { 8192, 24576, 49152, 65536, 73728, 81920, 86016, 94208, 102400 };
  const int nsrc[9]  = { 128, 128, 128, 128, 64, 64, 32, 64, 64 };
  const int ksrc[9]  = { 52, 128, 180, 128, 128, 128, 128, 128, 128 };
  const int kpad[9]  = { 64, 128, 192, 128, 128, 128, 128, 128, 128 };
  for (int i = 0; i < 9; ++i) { PP.src[i]=srcs[i]; PP.end[i]=ends[i]; PP.Nsrc[i]=nsrc[i]; PP.Ksrc[i]=ksrc[i]; PP.Kpad[i]=kpad[i]; }
  PP.wt = (short*)d_ws;
  hipLaunchKernelGGL(prep_weights, dim3((WT_ALLOC+255)/256), dim3(256), 0, stream, PP);

  Params P;
  P.x = in[0]; P.freq = in[1]; P.tables = in[2];
  P.b0 = in[4]; P.b1 = in[6]; P.b2 = in[8]; P.b3 = in[10];
  P.e_b1 = in[12]; P.e_w2 = in[13]; P.e_b2 = in[14];
  P.m_b1 = in[16]; P.m_w2 = in[17]; P.m_b2 = in[18];
  P.p_b1 = in[20]; P.p_w2 = in[21]; P.p_b2 = in[22];
  P.mat_b1 = in[24]; P.mat_w2 = in[25]; P.mat_b2 = in[26];
  P.s_b1 = in[28]; P.s_w2 = in[29]; P.s_b2 = in[30];
  P.e_g = in[31]; P.e_be = in[32]; P.m_g = in[33]; P.m_be = in[34];
  P.wt = (const short*)d_ws;
  P.feat = (const unsigned*)((const char*)d_ws + WS_FEAT_OFF);
  P.out = (float*)d_out;
  P.N = N;

  // staging tables for em_nerf4
  const float* ssrc[18] = { in[4], in[6], in[8], in[10], in[12], in[16], in[20], in[24], in[28],
                            in[14], in[18], in[22], in[26], in[30],
                            in[31], in[32], in[33], in[34] };
  const int sdst[18] = { 0,128,256,384, 512,576,640,672,736, 800,803,806,812,815, 819,883,947,1011 };
  const int scnt[18] = { 128,128,128,128, 64,64,32,64,64, 3,3,6,3,4, 64,64,64,64 };
  const float* wsrc[5] = { in[13], in[17], in[21], in[25], in[29] };
  const int wdst[5] = { 0,192,384,576,768 };
  const int wcnt[5] = { 192,192,192,192,256 };
  for (int i = 0; i < 18; ++i) { P.ssrc[i]=ssrc[i]; P.sdst[i]=sdst[i]; P.scnt[i]=scnt[i]; }
  for (int i = 0; i < 5; ++i)  { P.wsrc[i]=wsrc[i]; P.wdst[i]=wdst[i]; P.wcnt[i]=wcnt[i]; }

  const double B = exp((log(512.0) - log(16.0)) / 15.0);
  for (int l = 0; l < 16; ++l) {
    double r = 16.0 * pow(B, (double)l);
    int ri = (int)r;
    if (ri > 512) ri = 512;
    P.res[l] = ri;
  }

  const size_t need = (size_t)WS_FEAT_OFF + (size_t)N*16*4;
  const int blocks = (N + 63) / 64;

  if (ws_size >= need) {
    TabPrepParams TP;
    TP.tables = in[2];
    TP.tab8 = (unsigned*)((char*)d_ws + WS_TAB8_OFF);
    hipLaunchKernelGGL(tab_prep, dim3((16*524288/2 + 255)/256), dim3(256), 0, stream, TP);

    HashParams HP;
    HP.x = in[0];
    HP.tab8 = (const unsigned short*)((const char*)d_ws + WS_TAB8_OFF);
    HP.feat = (unsigned*)((char*)d_ws + WS_FEAT_OFF);
    HP.N = N;
    for (int l = 0; l < 16; ++l) HP.res[l] = P.res[l];
    const int chunks = (N + 255) / 256;
    hipLaunchKernelGGL(hash_encode8, dim3(chunks*16), dim3(256), 0, stream, HP);

    hipLaunchKernelGGL(em_nerf4, dim3(blocks), dim3(128), 0, stream, P);
  } else {
    hipLaunchKernelGGL(em_nerf_fallback, dim3(blocks), dim3(256), 0, stream, P);
  }
}

// Round 7
// 583.149 us; speedup vs baseline: 1.2327x; 1.2327x over previous
//
#include <hip/hip_runtime.h>
#include <math.h>

#define TMASK 524287   // 2^19 - 1
#define PM0 455773     // 73856093 % 2^19
#define PM1 475295     // 19349663 % 2^19
#define PM2 130999     // 83492791 % 2^19

typedef __attribute__((ext_vector_type(8))) short bf16x8;
typedef __attribute__((ext_vector_type(4))) float f32x4;

// Transposed-bf16 weight buffer layout in d_ws (element offsets, shorts):
#define OFF_W0   0       // [128][64]   (K=52  pad 64)
#define OFF_W1   8192    // [128][128]
#define OFF_W2   24576   // [128][192]  (K=180 pad 192)
#define OFF_W3   49152   // [128][128]
#define OFF_E    65536   // [64][128]   E,M contiguous (8 tiles)
#define OFF_P    81920   // [32][128]
#define OFF_MAT  86016   // [64][128]   MAT,S contiguous (8 tiles)
#define OFF_S    94208   // [64][128]
#define OFF_BD   102400  // [32][288] block-diagonal fused head-l2 matrix
#define WT_TOTAL 102400
#define WT_ALLOC 111616  // + BD region

// ws byte layout: wt | tab8 int8[16][524288][2] (16 MiB) | feat_pm uint[N][16]
#define WS_TAB8_OFF (WT_ALLOC*2)
#define TAB8_BYTES  (16u*524288u*2u)
#define WS_FEAT_OFF (WS_TAB8_OFF + TAB8_BYTES)

#define TAB_SCALE   131072.0f
#define TAB_INV     (1.0f/131072.0f)

// ---- em_nerf5 LDS layout: per-wave arena x2 + shared swf
#define A_FB   0        // bf16[32][72]; R2 f32[32][20] aliases (FB dead post trunk-L2)
#define A_H    4608     // bf16[32][136]
#define A_HL   13312    // bf16[32][168]  head-l2 staging (two halves)
#define ARENA5 24064
#define SWF5_OFF 48128  // f32[1075]
#define LDS5_TOTAL 52432

// swf indices
#define SB0 0
#define SB1 128
#define SB2 256
#define SB3 384
#define SEM 512    // e_b1|m_b1 (128)
#define SPB 640    // p_b1 (32)
#define SMS 672    // mat_b1|s_b1 (128)
#define SB2C 800   // e_b2 m_b2 p_b2 mat_b2 s_b2 (19)
#define SEG 819
#define SEBE 883
#define SMG 947
#define SMBE 1011

struct Params {
  const float* x; const float* freq; const float* tables;
  const float* b0; const float* b1; const float* b2; const float* b3;
  const float* e_b1; const float* e_w2; const float* e_b2; const float* e_g; const float* e_be;
  const float* m_b1; const float* m_w2; const float* m_b2; const float* m_g; const float* m_be;
  const float* p_b1; const float* p_w2; const float* p_b2;
  const float* mat_b1; const float* mat_w2; const float* mat_b2;
  const float* s_b1; const float* s_w2; const float* s_b2;
  const short* wt;
  const unsigned* feat;
  float* out;
  int N;
  int res[16];
  const float* ssrc[18]; int sdst[18]; int scnt[18];
};

struct HashParams {
  const float* x; const unsigned short* tab8; unsigned* feat; int N; int res[16];
};
struct TabPrepParams { const float* tables; unsigned* tab8; };
struct PrepParams {
  const float* src[9];
  int end[9]; int Nsrc[9]; int Ksrc[9]; int Kpad[9];
  short* wt;
};
struct BdParams {
  const float* e; const float* m; const float* p; const float* mat; const float* s;
  short* out;
};

__device__ __forceinline__ short f2bf(float f){
  union { float f; unsigned u; } v; v.f = f;
  unsigned r = v.u + 0x7fffu + ((v.u >> 16) & 1u);   // RNE
  return (short)(r >> 16);
}
__device__ __forceinline__ float bf2f(short s){
  union { unsigned u; float f; } v; v.u = ((unsigned)(unsigned short)s) << 16; return v.f;
}
__device__ __forceinline__ float sigmoid_(float v){ return 1.f/(1.f + expf(-v)); }

// ---------------- weight transpose+bf16 prep
__global__ __launch_bounds__(256)
void prep_weights(PrepParams P)
{
  int id = blockIdx.x*256 + threadIdx.x;
  if (id >= WT_TOTAL) return;
  int r = 0, base = 0;
  #pragma unroll
  for (int i = 0; i < 9; ++i) { if (id >= P.end[i]) { r = i+1; base = P.end[i]; } }
  const int rel = id - base;
  const int kp = P.Kpad[r];
  const int n = rel / kp;
  const int k = rel - n*kp;
  float v = 0.f;
  if (k < P.Ksrc[r]) v = P.src[r][k * P.Nsrc[r] + n];
  P.wt[id] = f2bf(v);
}

// ---------------- block-diagonal fused head-l2 matrix [32 n][288 k]
__global__ __launch_bounds__(256)
void prep_bd(BdParams P)
{
  int id = blockIdx.x*256 + threadIdx.x;
  if (id >= 32*288) return;
  const int n = id / 288, k = id - n*288;
  float v = 0.f;
  if      (n < 3  && k < 64)               v = P.e[k*3 + n];
  else if (n >= 3 && n < 6  && k >= 64  && k < 128) v = P.m[(k-64)*3 + (n-3)];
  else if (n >= 6 && n < 12 && k >= 128 && k < 160) v = P.p[(k-128)*6 + (n-6)];
  else if (n >= 12&& n < 15 && k >= 160 && k < 224) v = P.mat[(k-160)*3 + (n-12)];
  else if (n >= 15&& n < 19 && k >= 224 && k < 288) v = P.s[(k-224)*4 + (n-15)];
  P.out[id] = f2bf(v);
}

// ---------------- table quantize fp32 -> int8 (scale 2^17)
__global__ __launch_bounds__(256)
void tab_prep(TabPrepParams P)
{
  const unsigned id = blockIdx.x*256 + threadIdx.x;
  if (id >= 16u*524288u/2u) return;
  const float4 v = ((const float4*)P.tables)[id];
  int q0 = (int)fminf(fmaxf(rintf(v.x*TAB_SCALE), -127.f), 127.f);
  int q1 = (int)fminf(fmaxf(rintf(v.y*TAB_SCALE), -127.f), 127.f);
  int q2 = (int)fminf(fmaxf(rintf(v.z*TAB_SCALE), -127.f), 127.f);
  int q3 = (int)fminf(fmaxf(rintf(v.w*TAB_SCALE), -127.f), 127.f);
  unsigned pack = (q0 & 255) | ((q1 & 255) << 8) | ((q2 & 255) << 16) | ((q3 & 255) << 24);
  P.tab8[id] = pack;
}

// ---------------- XCD-partitioned hash gather: block b handles level (b & 15).
__global__ __launch_bounds__(256, 8)
void hash_encode8(HashParams P)
{
  const int b = blockIdx.x;
  const int l = b & 15;
  const int p = (b >> 4)*256 + threadIdx.x;
  if (p >= P.N) return;
  const float xs0 = fminf(fmaxf(P.x[p*3+0], 0.f), 1.f);
  const float xs1 = fminf(fmaxf(P.x[p*3+1], 0.f), 1.f);
  const float xs2 = fminf(fmaxf(P.x[p*3+2], 0.f), 1.f);
  const int res = P.res[l];
  const float rf = (float)(res-1);
  const float s0 = xs0*rf, s1 = xs1*rf, s2 = xs2*rf;
  int f0i = (int)s0; if (f0i > res-1) f0i = res-1;
  int f1i = (int)s1; if (f1i > res-1) f1i = res-1;
  int f2i = (int)s2; if (f2i > res-1) f2i = res-1;
  const float w0 = s0 - (float)f0i;
  const float w1 = s1 - (float)f1i;
  const float w2 = s2 - (float)f2i;
  int c0i = f0i+1; if (c0i > res-1) c0i = res-1;
  int c1i = f1i+1; if (c1i > res-1) c1i = res-1;
  int c2i = f2i+1; if (c2i > res-1) c2i = res-1;
  const int hx0 = (f0i*PM0) & TMASK, hx1 = (c0i*PM0) & TMASK;
  const int hy0 = (f1i*PM1) & TMASK, hy1 = (c1i*PM1) & TMASK;
  const int hz0 = (f2i*PM2) & TMASK, hz1 = (c2i*PM2) & TMASK;
  const unsigned short* tp = P.tab8 + ((size_t)l << 19);
  unsigned short tv[8];
  #pragma unroll
  for (int cn = 0; cn < 8; ++cn) {
    const int bx = (cn>>2)&1, by = (cn>>1)&1, bz = cn&1;
    const int hh = ((bx?hx1:hx0) + (by?hy1:hy0) + (bz?hz1:hz0)) & TMASK;
    tv[cn] = tp[hh];
  }
  float a0 = 0.f, a1 = 0.f;
  #pragma unroll
  for (int cn = 0; cn < 8; ++cn) {
    const int bx = (cn>>2)&1, by = (cn>>1)&1, bz = cn&1;
    const float cw = (bx?w0:1.f-w0)*(by?w1:1.f-w1)*(bz?w2:1.f-w2);
    a0 = fmaf(cw, (float)(int)(signed char)(tv[cn] & 0xff), a0);
    a1 = fmaf(cw, (float)(int)(signed char)(tv[cn] >> 8),   a1);
  }
  a0 *= TAB_INV; a1 *= TAB_INV;
  const unsigned pack = (unsigned)(unsigned short)f2bf(a0)
                      | ((unsigned)(unsigned short)f2bf(a1) << 16);
  P.feat[(size_t)p*16 + l] = pack;
}

// ---------------- M=32 MFMA phase with depth-1 B prefetch (ping-pong regs)
template<int NT, int KC>
__device__ __forceinline__ void gemm32(f32x4* acc0, f32x4* acc1,
    const short* A, int lda, const short* __restrict__ wt, int kpad, int kwoff,
    int n0, int q)
{
  const short* Ap0 = A + n0*lda + q*8;
  const short* Ap1 = Ap0 + 16*lda;
  const short* Bp  = wt + n0*kpad + kwoff + q*8;
  bf16x8 bc[NT], bn[NT];
  #pragma unroll
  for (int nt = 0; nt < NT; ++nt) bc[nt] = *(const bf16x8*)(Bp + nt*16*kpad);
  #pragma unroll
  for (int kc = 0; kc < KC; ++kc) {
    if (kc + 1 < KC) {
      #pragma unroll
      for (int nt = 0; nt < NT; ++nt)
        bn[nt] = *(const bf16x8*)(Bp + nt*16*kpad + (kc+1)*32);
    }
    const bf16x8 a0 = *(const bf16x8*)(Ap0 + kc*32);
    const bf16x8 a1 = *(const bf16x8*)(Ap1 + kc*32);
    #pragma unroll
    for (int nt = 0; nt < NT; ++nt) {
      acc0[nt] = __builtin_amdgcn_mfma_f32_16x16x32_bf16(a0, bc[nt], acc0[nt], 0, 0, 0);
      acc1[nt] = __builtin_amdgcn_mfma_f32_16x16x32_bf16(a1, bc[nt], acc1[nt], 0, 0, 0);
    }
    #pragma unroll
    for (int nt = 0; nt < NT; ++nt) bc[nt] = bn[nt];
  }
}

// trunk epilogue: bias + relu + f2bf -> LDS (C: col=lane&15, row=(lane>>4)*4+reg)
template<int NT>
__device__ __forceinline__ void epi_trunk(const f32x4* acc0, const f32x4* acc1,
    const float* bias, short* out, int ldo, int n0, int q)
{
  #pragma unroll
  for (int nt = 0; nt < NT; ++nt) {
    const float bv = bias[nt*16 + n0];
    #pragma unroll
    for (int r = 0; r < 4; ++r) {
      float v0 = fmaxf(acc0[nt][r] + bv, 0.f);
      float v1 = fmaxf(acc1[nt][r] + bv, 0.f);
      out[(q*4 + r)*ldo + nt*16 + n0]      = f2bf(v0);
      out[(16 + q*4 + r)*ldo + nt*16 + n0] = f2bf(v1);
    }
  }
}

__global__ __launch_bounds__(128)
void em_nerf5(Params P)
{
  __shared__ __align__(16) char smem[LDS5_TOTAL];
  const int tid = threadIdx.x;
  const int lane = tid & 63, wave = tid >> 6;
  char* arena = smem + wave*ARENA5;
  short* FB = (short*)(arena + A_FB);
  short* H  = (short*)(arena + A_H);
  short* HL = (short*)(arena + A_HL);
  float* R2 = (float*)(arena + A_FB);
  float* swf = (float*)(smem + SWF5_OFF);
  const int n0 = lane & 15, q = lane >> 4;
  const int p0pt = blockIdx.x*64 + wave*32;

  // feat loads issued first (latency overlaps staging)
  uint4 fv[2];
  #pragma unroll
  for (int pass = 0; pass < 2; ++pass) {
    const int idx = lane + pass*64;
    const int pl = idx >> 2, lq = idx & 3;
    int gp = p0pt + pl; if (gp >= P.N) gp = P.N - 1;
    fv[pass] = *(const uint4*)(P.feat + (size_t)gp*16 + lq*4);
  }

  // stage biases / LN params (looped)
  #pragma clang loop unroll(disable)
  for (int r = 0; r < 18; ++r)
    for (int i = tid; i < P.scnt[r]; i += 128) swf[P.sdst[r] + i] = P.ssrc[r][i];

  #pragma unroll
  for (int pass = 0; pass < 2; ++pass) {
    const int idx = lane + pass*64;
    const int pl = idx >> 2, lq = idx & 3;
    *(uint4*)&FB[pl*72 + lq*8] = fv[pass];
  }
  if (lane < 32) {
    int gp = p0pt + lane; if (gp >= P.N) gp = P.N - 1;
    float fr = P.freq[gp];
    fr = fminf(fmaxf(fr, 1e6f), 1e12f);
    const float nf = (log10f(fr) - 6.f) * (1.f/6.f);
    float a = 3.14159274101257324f * nf;
    #pragma clang loop unroll(disable)
    for (int i = 0; i < 10; ++i) {
      FB[lane*72 + 32 + 2*i] = f2bf(sinf(a));
      FB[lane*72 + 33 + 2*i] = f2bf(cosf(a));
      a = a * 2.f;
    }
    #pragma unroll
    for (int k = 52; k < 64; ++k) FB[lane*72 + k] = 0;
  }
  __syncthreads();

  // ---- trunk
  { f32x4 a0[8] = {}, a1[8] = {};
    gemm32<8,2>(a0, a1, FB, 72, P.wt + OFF_W0, 64, 0, n0, q);
    epi_trunk<8>(a0, a1, swf + SB0, H, 136, n0, q); }
  { f32x4 a0[8] = {}, a1[8] = {};
    gemm32<8,4>(a0, a1, H, 136, P.wt + OFF_W1, 128, 0, n0, q);
    epi_trunk<8>(a0, a1, swf + SB1, H, 136, n0, q); }
  { f32x4 a0[8] = {}, a1[8] = {};
    gemm32<8,4>(a0, a1, H, 136, P.wt + OFF_W2, 192, 0, n0, q);
    gemm32<8,2>(a0, a1, FB, 72, P.wt + OFF_W2, 192, 128, n0, q);
    epi_trunk<8>(a0, a1, swf + SB2, H, 136, n0, q); }
  { f32x4 a0[8] = {}, a1[8] = {};
    gemm32<8,4>(a0, a1, H, 136, P.wt + OFF_W3, 128, 0, n0, q);
    epi_trunk<8>(a0, a1, swf + SB3, H, 136, n0, q); }

  // ---- head l1 phase A: E(4 tiles)+M(4 tiles); LN in-register
  { f32x4 a0[8] = {}, a1[8] = {};
    gemm32<8,4>(a0, a1, H, 136, P.wt + OFF_E, 128, 0, n0, q);
    #pragma unroll
    for (int nt = 0; nt < 8; ++nt) {
      const float bv = swf[SEM + nt*16 + n0];
      #pragma unroll
      for (int r = 0; r < 4; ++r) { a0[nt][r] += bv; a1[nt][r] += bv; }
    }
    float mE[2][4], iE[2][4], mM[2][4], iM[2][4];
    #pragma unroll
    for (int s = 0; s < 2; ++s) {
      const f32x4* A_ = s ? a1 : a0;
      #pragma unroll
      for (int r = 0; r < 4; ++r) {
        float se = 0.f, qe = 0.f, sm = 0.f, qm = 0.f;
        #pragma unroll
        for (int t = 0; t < 4; ++t) { const float x = A_[t][r]; se += x; qe = fmaf(x,x,qe); }
        #pragma unroll
        for (int t = 4; t < 8; ++t) { const float x = A_[t][r]; sm += x; qm = fmaf(x,x,qm); }
        #pragma unroll
        for (int msk = 1; msk < 16; msk <<= 1) {
          se += __shfl_xor(se, msk, 64);
          qe += __shfl_xor(qe, msk, 64);
          sm += __shfl_xor(sm, msk, 64);
          qm += __shfl_xor(qm, msk, 64);
        }
        const float me = se*(1.f/64.f), mm = sm*(1.f/64.f);
        mE[s][r] = me; mM[s][r] = mm;
        iE[s][r] = 1.f / sqrtf(qe*(1.f/64.f) - me*me + 1e-5f);
        iM[s][r] = 1.f / sqrtf(qm*(1.f/64.f) - mm*mm + 1e-5f);
      }
    }
    #pragma unroll
    for (int t = 0; t < 8; ++t) {
      const int col = (t < 4) ? t*16 + n0 : 64 + (t-4)*16 + n0;
      const float g  = (t < 4) ? swf[SEG  + t*16 + n0] : swf[SMG  + (t-4)*16 + n0];
      const float be = (t < 4) ? swf[SEBE + t*16 + n0] : swf[SMBE + (t-4)*16 + n0];
      #pragma unroll
      for (int s = 0; s < 2; ++s) {
        const f32x4* A_ = s ? a1 : a0;
        #pragma unroll
        for (int r = 0; r < 4; ++r) {
          const float mn = (t < 4) ? mE[s][r] : mM[s][r];
          const float iv = (t < 4) ? iE[s][r] : iM[s][r];
          float v = (A_[t][r] - mn)*iv*g + be;
          v = fmaxf(v, 0.f);
          HL[(s*16 + q*4 + r)*168 + col] = f2bf(v);
        }
      }
    }
  }

  // ---- head l1 phase B: P (2 tiles) -> HL cols 128..159
  { f32x4 a0[2] = {}, a1[2] = {};
    gemm32<2,4>(a0, a1, H, 136, P.wt + OFF_P, 128, 0, n0, q);
    #pragma unroll
    for (int t = 0; t < 2; ++t) {
      const float bv = swf[SPB + t*16 + n0];
      const int col = 128 + t*16 + n0;
      #pragma unroll
      for (int s = 0; s < 2; ++s) {
        const f32x4* A_ = s ? a1 : a0;
        #pragma unroll
        for (int r = 0; r < 4; ++r)
          HL[(s*16 + q*4 + r)*168 + col] = f2bf(fmaxf(A_[t][r] + bv, 0.f));
      }
    }
  }

  // ---- fused head l2: partA over k 0..159 (E,M,P)
  f32x4 o0[2] = {}, o1[2] = {};
  gemm32<2,5>(o0, o1, HL, 168, P.wt + OFF_BD, 288, 0, n0, q);

  // ---- head l1 phase C: MAT(4)+S(4) -> HL cols 0..127 (overwrite)
  { f32x4 a0[8] = {}, a1[8] = {};
    gemm32<8,4>(a0, a1, H, 136, P.wt + OFF_MAT, 128, 0, n0, q);
    #pragma unroll
    for (int t = 0; t < 8; ++t) {
      const float bv = swf[SMS + t*16 + n0];
      const int col = t*16 + n0;
      #pragma unroll
      for (int s = 0; s < 2; ++s) {
        const f32x4* A_ = s ? a1 : a0;
        #pragma unroll
        for (int r = 0; r < 4; ++r)
          HL[(s*16 + q*4 + r)*168 + col] = f2bf(fmaxf(A_[t][r] + bv, 0.f));
      }
    }
  }

  // ---- fused head l2: partB over k 160..287 (MAT,S), accumulate
  gemm32<2,4>(o0, o1, HL, 168, P.wt + OFF_BD, 288, 160, n0, q);

  // l2 epilogue: tile0 -> j=n0 (0..15), tile1 -> j=16+n0 (n0<3)
  #pragma unroll
  for (int s = 0; s < 2; ++s) {
    const f32x4* O_ = s ? o1 : o0;
    #pragma unroll
    for (int r = 0; r < 4; ++r) {
      const int p = s*16 + q*4 + r;
      float v0 = O_[0][r] + swf[SB2C + n0];
      if (n0 < 6) v0 = tanhf(v0);
      R2[p*20 + n0] = v0;
      if (n0 < 3)
        R2[p*20 + 16 + n0] = O_[1][r] + swf[SB2C + 16 + n0];
    }
  }

  // ---- final packing (TIME=0 -> cos(phases))
  if (lane < 32) {
    const int gp = p0pt + lane;
    if (gp < P.N) {
      const float* r = R2 + lane*20;
      float* o = P.out + (size_t)gp*13;
      o[0] = r[0]*cosf(r[6]);
      o[1] = r[1]*cosf(r[7]);
      o[2] = r[2]*cosf(r[8]);
      o[3] = r[3]*cosf(r[9]);
      o[4] = r[4]*cosf(r[10]);
      o[5] = r[5]*cosf(r[11]);
      o[6] = 1.f + sigmoid_(r[12])*10.f;
      o[7] = 1.f + sigmoid_(r[13])*2.f;
      o[8] = sigmoid_(r[14])*0.01f;
      o[9]  = r[15];
      o[10] = r[16];
      o[11] = r[17];
      o[12] = r[18];
    }
  }
}

// ================= fallback fused kernel (ws too small) =================
__global__ __launch_bounds__(256, 3)
void em_nerf_fallback(Params P)
{
  __shared__ __align__(16) char smem[44288];
  short* featB = (short*)smem;
  short* hA    = (short*)(smem + 9216);
  short* hB    = (short*)(smem + 9216 + 17664);
  float* headF = (float*)(smem + 9216);
  float* res2  = (float*)smem;
  __shared__ int s_res[16];

  const int tid = threadIdx.x;
  if (tid < 16) s_res[tid] = P.res[tid];
  __syncthreads();
  {
    const int p = tid & 63;
    const int g = tid >> 6;
    int gp = blockIdx.x*64 + p; if (gp >= P.N) gp = P.N - 1;
    const float xs0 = fminf(fmaxf(P.x[gp*3+0], 0.f), 1.f);
    const float xs1 = fminf(fmaxf(P.x[gp*3+1], 0.f), 1.f);
    const float xs2 = fminf(fmaxf(P.x[gp*3+2], 0.f), 1.f);
    #pragma unroll
    for (int j = 0; j < 4; ++j) {
      const int l = g*4 + j;
      const int res = s_res[l];
      const float rf = (float)(res-1);
      const float s0 = xs0*rf, s1 = xs1*rf, s2 = xs2*rf;
      int f0i = (int)s0; if (f0i > res-1) f0i = res-1;
      int f1i = (int)s1; if (f1i > res-1) f1i = res-1;
      int f2i = (int)s2; if (f2i > res-1) f2i = res-1;
      const float w0 = s0 - (float)f0i;
      const float w1 = s1 - (float)f1i;
      const float w2 = s2 - (float)f2i;
      int c0i = f0i+1; if (c0i > res-1) c0i = res-1;
      int c1i = f1i+1; if (c1i > res-1) c1i = res-1;
      int c2i = f2i+1; if (c2i > res-1) c2i = res-1;
      const int hx0 = (f0i*PM0) & TMASK, hx1 = (c0i*PM0) & TMASK;
      const int hy0 = (f1i*PM1) & TMASK, hy1 = (c1i*PM1) & TMASK;
      const int hz0 = (f2i*PM2) & TMASK, hz1 = (c2i*PM2) & TMASK;
      const float* tp = P.tables + ((size_t)l << 20);
      float a0 = 0.f, a1 = 0.f;
      #pragma unroll
      for (int cn = 0; cn < 8; ++cn) {
        const int bx = (cn>>2)&1, by = (cn>>1)&1, bz = cn&1;
        const int hh = ((bx?hx1:hx0) + (by?hy1:hy0) + (bz?hz1:hz0)) & TMASK;
        const float cw = (bx?w0:1.f-w0)*(by?w1:1.f-w1)*(bz?w2:1.f-w2);
        const float2 tv = *(const float2*)(tp + 2*hh);
        a0 = fmaf(cw, tv.x, a0);
        a1 = fmaf(cw, tv.y, a1);
      }
      featB[p*72 + 2*l]   = f2bf(a0);
      featB[p*72 + 2*l+1] = f2bf(a1);
    }
    if (g == 0) {
      float fr = P.freq[gp];
      fr = fminf(fmaxf(fr, 1e6f), 1e12f);
      const float nf = (log10f(fr) - 6.f) * (1.f/6.f);
      float a = 3.14159274101257324f * nf;
      #pragma unroll
      for (int i = 0; i < 10; ++i) {
        featB[p*72 + 32 + 2*i] = f2bf(sinf(a));
        featB[p*72 + 33 + 2*i] = f2bf(cosf(a));
        a = a * 2.f;
      }
    }
    if (g == 3) {
      #pragma unroll
      for (int k = 52; k < 64; ++k) featB[p*72 + k] = 0;
    }
  }
  __syncthreads();

  const int lane = tid & 63, wave = tid >> 6;
  const int n0 = lane & 15, q = lane >> 4;
  short* myA  = featB + wave*16*72;
  short* myH1 = hA + wave*16*136;
  short* myH2 = hB + wave*16*136;

  auto gemm1 = [&](const short* A, int lda, const short* wt, int kpad, int kwoff, int KC, f32x4* acc, int NT){
    const short* Ap = A + n0*lda + q*8;
    const short* Bp = wt + n0*kpad + kwoff + q*8;
    for (int kc = 0; kc < KC; ++kc) {
      bf16x8 a = *(const bf16x8*)(Ap + kc*32);
      for (int nt = 0; nt < NT; ++nt) {
        bf16x8 b = *(const bf16x8*)(Bp + nt*16*kpad + kc*32);
        acc[nt] = __builtin_amdgcn_mfma_f32_16x16x32_bf16(a, b, acc[nt], 0, 0, 0);
      }
    }
  };
  auto epi1 = [&](const f32x4* acc, const float* bias, short* out, int ldo, int NT, bool relu){
    for (int nt = 0; nt < NT; ++nt) {
      const float bv = bias[nt*16 + n0];
      for (int r = 0; r < 4; ++r) {
        float v = acc[nt][r] + bv;
        if (relu) v = fmaxf(v, 0.f);
        out[(q*4 + r)*ldo + nt*16 + n0] = f2bf(v);
      }
    }
  };

  { f32x4 acc[8] = {}; gemm1(myA, 72, P.wt + OFF_W0, 64, 0, 2, acc, 8);  epi1(acc, P.b0, myH1, 136, 8, true); }
  __syncthreads();
  { f32x4 acc[8] = {}; gemm1(myH1, 136, P.wt + OFF_W1, 128, 0, 4, acc, 8); epi1(acc, P.b1, myH2, 136, 8, true); }
  __syncthreads();
  { f32x4 acc[8] = {}; gemm1(myH2, 136, P.wt + OFF_W2, 192, 0, 4, acc, 8);
    gemm1(myA, 72, P.wt + OFF_W2, 192, 128, 2, acc, 8); epi1(acc, P.b2, myH1, 136, 8, true); }
  __syncthreads();
  { f32x4 acc[8] = {}; gemm1(myH1, 136, P.wt + OFF_W3, 128, 0, 4, acc, 8); epi1(acc, P.b3, myH2, 136, 8, true); }
  __syncthreads();

  float* hf = headF + wave*16*69;
  auto head1f = [&](const short* wt, const float* bias, int NT, bool relu){
    f32x4 acc[4] = {};
    gemm1(myH2, 136, wt, 128, 0, 4, acc, NT);
    for (int nt = 0; nt < NT; ++nt) {
      const float bv = bias[nt*16 + n0];
      for (int r = 0; r < 4; ++r) {
        float v = acc[nt][r] + bv;
        if (relu) v = fmaxf(v, 0.f);
        hf[(q*4 + r)*69 + nt*16 + n0] = v;
      }
    }
  };
  auto l2 = [&](int OC2, int K2, bool ln, bool th, const float* g, const float* be,
                const float* W2, const float* b2, int slot){
    __syncthreads();
    if (tid < 64) {
      const float* row = headF + tid*69;
      float mn = 0.f, iv = 1.f;
      if (ln) {
        float s = 0.f;
        for (int k = 0; k < K2; ++k) s += row[k];
        mn = s/(float)K2;
        float vv = 0.f;
        for (int k = 0; k < K2; ++k) { float d = row[k]-mn; vv = fmaf(d,d,vv); }
        iv = 1.f/sqrtf(vv/(float)K2 + 1e-5f);
      }
      for (int j = 0; j < OC2; ++j) {
        float acc = b2[j];
        for (int k = 0; k < K2; ++k) {
          float xv = row[k];
          if (ln) xv = (xv-mn)*iv*g[k] + be[k];
          xv = fmaxf(xv, 0.f);
          acc = fmaf(xv, W2[k*OC2+j], acc);
        }
        res2[tid*20 + slot + j] = th ? tanhf(acc) : acc;
      }
    }
    __syncthreads();
  };

  head1f(P.wt + OFF_E, P.e_b1, 4, false); l2(3, 64, true,  true,  P.e_g, P.e_be, P.e_w2, P.e_b2, 0);
  head1f(P.wt + OFF_E + 8192, P.m_b1, 4, false); l2(3, 64, true, true, P.m_g, P.m_be, P.m_w2, P.m_b2, 3);
  head1f(P.wt + OFF_P, P.p_b1, 2, true);  l2(6, 32, false, false, 0, 0, P.p_w2, P.p_b2, 6);
  head1f(P.wt + OFF_MAT, P.mat_b1, 4, true); l2(3, 64, false, false, 0, 0, P.mat_w2, P.mat_b2, 12);
  head1f(P.wt + OFF_S, P.s_b1, 4, true);  l2(4, 64, false, false, 0, 0, P.s_w2, P.s_b2, 15);

  if (tid < 64) {
    const int gp = blockIdx.x*64 + tid;
    if (gp < P.N) {
      const float* r = res2 + tid*20;
      float* o = P.out + (size_t)gp*13;
      o[0] = r[0]*cosf(r[6]);
      o[1] = r[1]*cosf(r[7]);
      o[2] = r[2]*cosf(r[8]);
      o[3] = r[3]*cosf(r[9]);
      o[4] = r[4]*cosf(r[10]);
      o[5] = r[5]*cosf(r[11]);
      o[6] = 1.f + sigmoid_(r[12])*10.f;
      o[7] = 1.f + sigmoid_(r[13])*2.f;
      o[8] = sigmoid_(r[14])*0.01f;
      o[9]  = r[15];
      o[10] = r[16];
      o[11] = r[17];
      o[12] = r[18];
    }
  }
}

extern "C" void kernel_launch(void* const* d_in, const int* in_sizes, int n_in,
                              void* d_out, int out_size, void* d_ws, size_t ws_size,
                              hipStream_t stream) {
  (void)n_in; (void)out_size;
  const float** in = (const float**)d_in;
  const int N = in_sizes[0] / 3;

  PrepParams PP;
  const float* srcs[9] = { in[3], in[5], in[7], in[9], in[11], in[15], in[19], in[23], in[27] };
  const int ends[9]  = { 8192, 24576, 49152, 65536, 73728, 81920, 86016, 94208, 102400 };
  const int nsrc[9]  = { 128, 128, 128, 128, 64, 64, 32, 64, 64 };
  const int ksrc[9]  = { 52, 128, 180, 128, 128, 128, 128, 128, 128 };
  const int kpad[9]  = { 64, 128, 192, 128, 128, 128, 128, 128, 128 };
  for (int i = 0; i < 9; ++i) { PP.src[i]=srcs[i]; PP.end[i]=ends[i]; PP.Nsrc[i]=nsrc[i]; PP.Ksrc[i]=ksrc[i]; PP.Kpad[i]=kpad[i]; }
  PP.wt = (short*)d_ws;
  hipLaunchKernelGGL(prep_weights, dim3((WT_TOTAL+255)/256), dim3(256), 0, stream, PP);

  BdParams BP;
  BP.e = in[13]; BP.m = in[17]; BP.p = in[21]; BP.mat = in[25]; BP.s = in[29];
  BP.out = (short*)d_ws + OFF_BD;
  hipLaunchKernelGGL(prep_bd, dim3((32*288 + 255)/256), dim3(256), 0, stream, BP);

  Params P;
  P.x = in[0]; P.freq = in[1]; P.tables = in[2];
  P.b0 = in[4]; P.b1 = in[6]; P.b2 = in[8]; P.b3 = in[10];
  P.e_b1 = in[12]; P.e_w2 = in[13]; P.e_b2 = in[14];
  P.m_b1 = in[16]; P.m_w2 = in[17]; P.m_b2 = in[18];
  P.p_b1 = in[20]; P.p_w2 = in[21]; P.p_b2 = in[22];
  P.mat_b1 = in[24]; P.mat_w2 = in[25]; P.mat_b2 = in[26];
  P.s_b1 = in[28]; P.s_w2 = in[29]; P.s_b2 = in[30];
  P.e_g = in[31]; P.e_be = in[32]; P.m_g = in[33]; P.m_be = in[34];
  P.wt = (const short*)d_ws;
  P.feat = (const unsigned*)((const char*)d_ws + WS_FEAT_OFF);
  P.out = (float*)d_out;
  P.N = N;

  const float* ssrc[18] = { in[4], in[6], in[8], in[10],
                            in[12], in[16], in[20], in[24], in[28],
                            in[14], in[18], in[22], in[26], in[30],
                            in[31], in[32], in[33], in[34] };
  const int sdst[18] = { 0,128,256,384, 512,576,640,672,736, 800,803,806,812,815, 819,883,947,1011 };
  const int scnt[18] = { 128,128,128,128, 64,64,32,64,64, 3,3,6,3,4, 64,64,64,64 };
  for (int i = 0; i < 18; ++i) { P.ssrc[i]=ssrc[i]; P.sdst[i]=sdst[i]; P.scnt[i]=scnt[i]; }

  const double B = exp((log(512.0) - log(16.0)) / 15.0);
  for (int l = 0; l < 16; ++l) {
    double r = 16.0 * pow(B, (double)l);
    int ri = (int)r;
    if (ri > 512) ri = 512;
    P.res[l] = ri;
  }

  const size_t need = (size_t)WS_FEAT_OFF + (size_t)N*16*4;
  const int blocks = (N + 63) / 64;

  if (ws_size >= need) {
    TabPrepParams TP;
    TP.tables = in[2];
    TP.tab8 = (unsigned*)((char*)d_ws + WS_TAB8_OFF);
    hipLaunchKernelGGL(tab_prep, dim3((16*524288/2 + 255)/256), dim3(256), 0, stream, TP);

    HashParams HP;
    HP.x = in[0];
    HP.tab8 = (const unsigned short*)((const char*)d_ws + WS_TAB8_OFF);
    HP.feat = (unsigned*)((char*)d_ws + WS_FEAT_OFF);
    HP.N = N;
    for (int l = 0; l < 16; ++l) HP.res[l] = P.res[l];
    const int chunks = (N + 255) / 256;
    hipLaunchKernelGGL(hash_encode8, dim3(chunks*16), dim3(256), 0, stream, HP);

    hipLaunchKernelGGL(em_nerf5, dim3(blocks), dim3(128), 0, stream, P);
  } else {
    hipLaunchKernelGGL(em_nerf_fallback, dim3(blocks), dim3(256), 0, stream, P);
  }
}